// Round 12
// baseline (181.987 us; speedup 1.0000x reference)
//
#include <hip/hip_runtime.h>

#define NT 64
#define NB 8192
#define NS 32
#define NF 16
#define DT 0.05f

typedef float f32x2 __attribute__((ext_vector_type(2)));
typedef float f32x4 __attribute__((ext_vector_type(4)));

// scalar tanh(x) = 1 - 2/(1 + exp2(K x)), K = 2*log2(e).
__device__ __forceinline__ float tanh1(float x) {
    const float K = 2.8853900817779268f;
    float e = __builtin_amdgcn_exp2f(K * x);
    float r = __builtin_amdgcn_rcpf(e + 1.0f);
    return fmaf(-2.0f, r, 1.0f);
}

// xor-16 lane exchange via ds_swizzle (BitMode offset 0x401F): lane p <-> p+16
// within each 32-lane half. R2-validated. Partner row of the same batch.
__device__ __forceinline__ float swz16f(float v) {
    return __int_as_float(__builtin_amdgcn_ds_swizzle(__float_as_int(v), 0x401F));
}

// R10/R11 post-mortem: VGPR_Count=64 vs ~112-float live set; back-computed
// ~8.7 cyc avg dependent latency/instr = scratch spill-reload traffic is the
// wall (L2-hit scratch ~50cyc, invisible in FETCH_SIZE). 4 rounds of
// allocator-fighting failed -> shrink the live set under the budget instead.
//
// Lane map: lane = b*32 + h*16 + p. b in [0,2) = batch within wave, h in
// [0,2) = OUTPUT ROW within the state pair (this lane computes row o = 2p+h),
// p in [0,16) = state pair. Per-lane invariants: W row o = 32 floats (16
// f32x2 column-pairs, rotation-gathered), U row o = 16 floats, forces 16 ->
// live ~84 floats: fits even a 6-wave-chasing allocator (85). 2 batches/wave
// -> 4096 waves = 4/SIMD (2x TLP of R10). Hop mechanism is UNCHANGED from
// the passing R6/R10 kernels: direct ror:j on original y, W at q=(p+dir*j);
// no pre-rotation composition (R11's failed novelty). Pair rebuilt after
// each iterate with one swz16 (R2-validated) + constant-index selects.
__global__ __launch_bounds__(256, 4) void rnes_kernel(
    const float* __restrict__ y0,
    const float* __restrict__ forces,
    const float* __restrict__ W,
    const float* __restrict__ U,
    const float* __restrict__ bias,
    float* __restrict__ out)
{
    const int lane = threadIdx.x & 63;
    const int wv   = threadIdx.x >> 6;
    const int b    = lane >> 5;
    const int h    = (lane >> 4) & 1;
    const int p    = lane & 15;
    const int batch = blockIdx.x * 8 + wv * 2 + b;
    const int o    = 2 * p + h;          // this lane's output row

    // One-time DPP direction probe: after ror:1 this lane holds the p it
    // received from; rotations compose, so ror:j delivers (p + dir*j) & 15.
    const int got = __builtin_amdgcn_update_dpp(0, p, 0x121, 0xF, 0xF, true) & 15;
    const int dir = (got == ((p + 1) & 15)) ? 1 : 15;

    // W row o gathered in rotation order: W2[j] = (W[o][2q], W[o][2q+1]),
    // q = (p + dir*j) & 15. 32 VGPRs.
    f32x2 W2[16];
#pragma unroll
    for (int j = 0; j < 16; ++j) {
        const int q = (p + dir * j) & 15;
        W2[j] = *(const f32x2*)(W + o * NS + 2 * q);
    }
    // U row o as packed feature pairs. 16 VGPRs.
    f32x2 U2[8];
#pragma unroll
    for (int f = 0; f < 8; ++f)
        U2[f] = *(const f32x2*)(U + o * NF + 2 * f);
    const float bo = bias[o];

    // y_prev pair, out[0] = y0 (h=0 stores the pair).
    f32x2 yp = *(const f32x2*)(y0 + (size_t)batch * NS + 2 * p);
    if (h == 0)
        __builtin_nontemporal_store(yp, (f32x2*)(out + (size_t)batch * NS + 2 * p));
    f32x2 ypp = yp;   // predictor history; k=1 extrapolation collapses to yp

    // register prefetch of forces[1]: full 16 features (broadcast per group).
    const size_t fstep = (size_t)NB * NF;
    const f32x4* fb = (const f32x4*)(forces + (size_t)batch * NF);
    f32x4 upf[4];
#pragma unroll
    for (int j = 0; j < 4; ++j)
        upf[j] = __builtin_nontemporal_load(&fb[(fstep >> 2) + j]);

    for (int k = 1; k < NT; ++k) {
        // fu (scalar, row o) = b[o] + U[o,:] u. Two packed chains of 4.
        f32x2 sA = (f32x2){0.f, 0.f}, sB = (f32x2){0.f, 0.f};
#pragma unroll
        for (int f = 0; f < 8; f += 2) {
            f32x4 u4 = upf[f >> 1];
            f32x2 u20 = (f32x2){u4[0], u4[1]};
            f32x2 u21 = (f32x2){u4[2], u4[3]};
            sA = U2[f]     * u20 + sA;
            sB = U2[f + 1] * u21 + sB;
        }
        const float fu = bo + (sA[0] + sA[1]) + (sB[0] + sB[1]);

        // prefetch next step's forces (in flight across the iterations)
        {
            int kn = (k + 1 < NT) ? (k + 1) : (NT - 1);
#pragma unroll
            for (int j = 0; j < 4; ++j)
                upf[j] = __builtin_nontemporal_load(&fb[(size_t)kn * (fstep >> 2) + j]);
        }

        const float ypo = h ? yp[1] : yp[0];   // own-row y_prev (const idx)

        // predictor: linear extrapolation on the pair (R10-validated).
        f32x2 y;
        y[0] = yp[0] + (yp[0] - ypp[0]);
        y[1] = yp[1] + (yp[1] - ypp[1]);

        // corrector: y[o] <- yp[o] + DT*tanh(W[o,:] y + fu). 15 INDEPENDENT
        // ror:j hops on the ORIGINAL pair (R6/R10-validated delivery); two
        // packed accumulator chains (depth 8); pair rebuilt via swz16.
        auto iterate = [&]() {
            const int y0i = __float_as_int(y[0]);
            const int y1i = __float_as_int(y[1]);
            f32x2 acc0 = (f32x2){fu, 0.f};
            f32x2 acc1 = (f32x2){0.f, 0.f};
            // j = 0: own pair, no hop
            acc0 = W2[0] * y + acc0;
#define RNES_HOP(J)                                                            \
            {                                                                  \
                f32x2 yq;                                                      \
                yq[0] = __int_as_float(__builtin_amdgcn_update_dpp(            \
                    0, y0i, 0x120 + (J), 0xF, 0xF, true));                     \
                yq[1] = __int_as_float(__builtin_amdgcn_update_dpp(            \
                    0, y1i, 0x120 + (J), 0xF, 0xF, true));                     \
                if ((J) & 1) acc1 = W2[J] * yq + acc1;                         \
                else         acc0 = W2[J] * yq + acc0;                         \
            }
            RNES_HOP(1)  RNES_HOP(2)  RNES_HOP(3)  RNES_HOP(4)
            RNES_HOP(5)  RNES_HOP(6)  RNES_HOP(7)  RNES_HOP(8)
            RNES_HOP(9)  RNES_HOP(10) RNES_HOP(11) RNES_HOP(12)
            RNES_HOP(13) RNES_HOP(14) RNES_HOP(15)
#undef RNES_HOP
            const float z = (acc0[0] + acc0[1]) + (acc1[0] + acc1[1]);
            const float yn = fmaf(DT, tanh1(z), ypo);     // own row o
            const float yo = swz16f(yn);                  // partner row
            y[0] = h ? yo : yn;   // row 2p
            y[1] = h ? yn : yo;   // row 2p+1  (both rows: identical pair)
        };
        iterate();
        iterate();
        if (k == 1) iterate();   // no extrapolation history at k=1

        ypp = yp;
        yp = y;
        if (h == 0)
            __builtin_nontemporal_store(y, (f32x2*)(out + ((size_t)k * NB + batch) * NS + 2 * p));
    }
}

extern "C" void kernel_launch(void* const* d_in, const int* in_sizes, int n_in,
                              void* d_out, int out_size, void* d_ws, size_t ws_size,
                              hipStream_t stream) {
    const float* y0     = (const float*)d_in[0];
    const float* forces = (const float*)d_in[1];
    const float* W      = (const float*)d_in[2];
    const float* U      = (const float*)d_in[3];
    const float* b      = (const float*)d_in[4];
    float* out = (float*)d_out;

    dim3 grid(NB / 8);    // 1024 blocks x 4 waves x 2 batches = 8192
    dim3 block(256);
    rnes_kernel<<<grid, block, 0, stream>>>(y0, forces, W, U, b, out);
}

// Round 13
// 152.072 us; speedup vs baseline: 1.1967x; 1.1967x over previous
//
#include <hip/hip_runtime.h>

#define NT 64
#define NB 8192
#define NS 32
#define NF 16
#define DT 0.05f

typedef float f32x4 __attribute__((ext_vector_type(4)));
typedef short s16x8 __attribute__((ext_vector_type(8)));

// trunc-split f32 -> bf16 hi + bf16 lo (y ~= hi + lo, rel err ~2^-17)
__device__ __forceinline__ void bsplit(float v, unsigned short& hi, unsigned short& lo) {
    unsigned int u = __float_as_uint(v);
    hi = (unsigned short)(u >> 16);
    float rest = v - __uint_as_float(u & 0xFFFF0000u);
    lo = (unsigned short)(__float_as_uint(rest) >> 16);
}

__device__ __forceinline__ void split8(const float* p, s16x8& hi, s16x8& lo) {
#pragma unroll
    for (int e = 0; e < 8; ++e) {
        unsigned short hs, ls;
        bsplit(p[e], hs, ls);
        hi[e] = (short)hs;
        lo[e] = (short)ls;
    }
}

// tanh(x) = 1 - 2/(1 + exp2(K x)), K = 2*log2(e).
__device__ __forceinline__ float tanh1(float x) {
    const float K = 2.8853900817779268f;
    float e = __builtin_amdgcn_exp2f(K * x);
    float r = __builtin_amdgcn_rcpf(e + 1.0f);
    return fmaf(-2.0f, r, 1.0f);
}

// R12 post-mortem: VALU-exchange structure is terminal at ~82us (12 rounds:
// DPP/LDS/packing/residency/occupancy all plateau; chain should be ~250
// cyc/step, measured 3150 — compiler-inserted reloads + exchange cost are
// irreducible at source level). Pivot: per-step z = y @ W^T IS a
// 16x16x32-shaped GEMM -> matrix cores.
//
// Structure: 1 wave = 16 batches for ALL time steps (512 blocks x 64 thr =
// 2 blocks/CU, no inter-wave communication ever).
//   A = W rows (constant, bf16 hi/lo in 4 frags), B = y (bf16 hi/lo staged
//   through a 2.5KB LDS repack between D-layout and B-layout each iterate),
//   D = z in f32 (lane: batch=l&15, states (l>>4)*4+r / +16) [m89-verified].
// Precision: z = Wh yh + Wh yl + Wl yh (3 MFMA, f32 acc) — rel err ~2^-16,
// far below measured bf16-granularity absmax 0.0156. fu likewise via MFMA
// with K padded 16->32 (zero lanes h>=2). Predictor-corrector (R10-validated):
// extrapolate + 2 iterations (3 at k==1).
__global__ __launch_bounds__(64) void rnes_kernel(
    const float* __restrict__ y0,
    const float* __restrict__ forces,
    const float* __restrict__ W,
    const float* __restrict__ U,
    const float* __restrict__ bias,
    float* __restrict__ out)
{
    const int lane = threadIdx.x;     // block = 1 wave
    const int m    = lane & 15;       // A-row o / B-col batch / D-col batch
    const int h    = lane >> 4;       // k-quad: this lane holds k = 8h..8h+7
    const int gb   = blockIdx.x * 16 + m;   // global batch

    // y staged as bf16 hi/lo: [16 batches][40 u16] (80B rows: b128-aligned,
    // bank spread <=2-way on both b64 writes and b128 reads).
    __shared__ __align__(16) unsigned short Yhi[16 * 40];
    __shared__ __align__(16) unsigned short Ylo[16 * 40];

    // A-fragments of W (constant): A[o][k=8h+e]; block0 o=m, block1 o=m+16.
    s16x8 WA0h, WA0l, WA1h, WA1l;
    split8(W + m * NS + 8 * h,        WA0h, WA0l);
    split8(W + (m + 16) * NS + 8 * h, WA1h, WA1l);

    // A-fragments of U, K padded 16->32 (k>=16 i.e. h>=2 lanes: zeros).
    s16x8 UA0h = {0,0,0,0,0,0,0,0}, UA0l = UA0h, UA1h = UA0h, UA1l = UA0h;
    if (h < 2) {
        split8(U + m * NF + 8 * h,        UA0h, UA0l);
        split8(U + (m + 16) * NF + 8 * h, UA1h, UA1l);
    }

    // bias in D layout: lane holds states 4h+r (A) and 16+4h+r (B).
    const f32x4 biasA = *(const f32x4*)(bias + 4 * h);
    const f32x4 biasB = *(const f32x4*)(bias + 16 + 4 * h);

    // y_prev in D layout; out[0] = y0.
    const float* yb = y0 + (size_t)gb * NS;
    f32x4 ypA = *(const f32x4*)(yb + 4 * h);
    f32x4 ypB = *(const f32x4*)(yb + 16 + 4 * h);
    {
        float* o0 = out + (size_t)gb * NS;
        __builtin_nontemporal_store(ypA, (f32x4*)(o0 + 4 * h));
        __builtin_nontemporal_store(ypB, (f32x4*)(o0 + 16 + 4 * h));
    }
    f32x4 yppA = ypA, yppB = ypB;

    // forces: B-operand of fu. Lane needs u[batch=m][f=8h+e], h<2 only.
    const size_t fstep = (size_t)NB * NF;
    const float* fba = forces + (size_t)gb * NF + 8 * h;
    f32x4 un0 = {0.f,0.f,0.f,0.f}, un1 = un0;
    if (h < 2) {
        un0 = __builtin_nontemporal_load((const f32x4*)(fba + fstep));
        un1 = __builtin_nontemporal_load((const f32x4*)(fba + fstep + 4));
    }

    for (int k = 1; k < NT; ++k) {
        // u B-fragments (bf16 hi/lo; zeros for h>=2 = padded K rows).
        s16x8 Buh = {0,0,0,0,0,0,0,0}, Bul = Buh;
        if (h < 2) {
            float uv[8] = {un0[0],un0[1],un0[2],un0[3],un1[0],un1[1],un1[2],un1[3]};
            split8(uv, Buh, Bul);
        }
        // fu = bias + U u  (3-term hi/lo split, 2 o-blocks, f32 accumulate)
        f32x4 fuA = biasA;
        fuA = __builtin_amdgcn_mfma_f32_16x16x32_bf16(UA0l, Buh, fuA, 0, 0, 0);
        fuA = __builtin_amdgcn_mfma_f32_16x16x32_bf16(UA0h, Bul, fuA, 0, 0, 0);
        fuA = __builtin_amdgcn_mfma_f32_16x16x32_bf16(UA0h, Buh, fuA, 0, 0, 0);
        f32x4 fuB = biasB;
        fuB = __builtin_amdgcn_mfma_f32_16x16x32_bf16(UA1l, Buh, fuB, 0, 0, 0);
        fuB = __builtin_amdgcn_mfma_f32_16x16x32_bf16(UA1h, Bul, fuB, 0, 0, 0);
        fuB = __builtin_amdgcn_mfma_f32_16x16x32_bf16(UA1h, Buh, fuB, 0, 0, 0);

        // prefetch next step's forces
        if (h < 2) {
            int kn = (k + 1 < NT) ? (k + 1) : (NT - 1);
            un0 = __builtin_nontemporal_load((const f32x4*)(fba + (size_t)kn * fstep));
            un1 = __builtin_nontemporal_load((const f32x4*)(fba + (size_t)kn * fstep + 4));
        }

        // predictor: linear extrapolation (R10-validated).
        f32x4 yA = ypA + (ypA - yppA);
        f32x4 yB = ypB + (ypB - yppB);

        // corrector: y <- yp + DT*tanh(W y + fu)
        auto iterate = [&]() {
            // split y -> bf16 hi/lo, write D-layout rows into LDS
            unsigned dh0, dh1, dl0, dl1;
            {
                unsigned short h0,h1,h2,h3,l0,l1,l2,l3;
                bsplit(yA[0],h0,l0); bsplit(yA[1],h1,l1);
                bsplit(yA[2],h2,l2); bsplit(yA[3],h3,l3);
                dh0 = (unsigned)h0 | ((unsigned)h1 << 16);
                dh1 = (unsigned)h2 | ((unsigned)h3 << 16);
                dl0 = (unsigned)l0 | ((unsigned)l1 << 16);
                dl1 = (unsigned)l2 | ((unsigned)l3 << 16);
            }
            *reinterpret_cast<unsigned long long*>(&Yhi[m * 40 + 4 * h]) =
                (unsigned long long)dh0 | ((unsigned long long)dh1 << 32);
            *reinterpret_cast<unsigned long long*>(&Ylo[m * 40 + 4 * h]) =
                (unsigned long long)dl0 | ((unsigned long long)dl1 << 32);
            {
                unsigned short h0,h1,h2,h3,l0,l1,l2,l3;
                bsplit(yB[0],h0,l0); bsplit(yB[1],h1,l1);
                bsplit(yB[2],h2,l2); bsplit(yB[3],h3,l3);
                dh0 = (unsigned)h0 | ((unsigned)h1 << 16);
                dh1 = (unsigned)h2 | ((unsigned)h3 << 16);
                dl0 = (unsigned)l0 | ((unsigned)l1 << 16);
                dl1 = (unsigned)l2 | ((unsigned)l3 << 16);
            }
            *reinterpret_cast<unsigned long long*>(&Yhi[m * 40 + 16 + 4 * h]) =
                (unsigned long long)dh0 | ((unsigned long long)dh1 << 32);
            *reinterpret_cast<unsigned long long*>(&Ylo[m * 40 + 16 + 4 * h]) =
                (unsigned long long)dl0 | ((unsigned long long)dl1 << 32);
            asm volatile("" ::: "memory");   // single-wave block: DS in-order

            // read B fragments: lane reads batch m, states 8h..8h+7 (b128)
            s16x8 Bh = *reinterpret_cast<const s16x8*>(&Yhi[m * 40 + 8 * h]);
            s16x8 Bl = *reinterpret_cast<const s16x8*>(&Ylo[m * 40 + 8 * h]);

            // z = W y + fu  (3-term hi/lo, 2 independent o-block chains)
            f32x4 zA = fuA;
            zA = __builtin_amdgcn_mfma_f32_16x16x32_bf16(WA0l, Bh, zA, 0, 0, 0);
            zA = __builtin_amdgcn_mfma_f32_16x16x32_bf16(WA0h, Bl, zA, 0, 0, 0);
            zA = __builtin_amdgcn_mfma_f32_16x16x32_bf16(WA0h, Bh, zA, 0, 0, 0);
            f32x4 zB = fuB;
            zB = __builtin_amdgcn_mfma_f32_16x16x32_bf16(WA1l, Bh, zB, 0, 0, 0);
            zB = __builtin_amdgcn_mfma_f32_16x16x32_bf16(WA1h, Bl, zB, 0, 0, 0);
            zB = __builtin_amdgcn_mfma_f32_16x16x32_bf16(WA1h, Bh, zB, 0, 0, 0);

#pragma unroll
            for (int r = 0; r < 4; ++r) {
                yA[r] = fmaf(DT, tanh1(zA[r]), ypA[r]);
                yB[r] = fmaf(DT, tanh1(zB[r]), ypB[r]);
            }
        };
        iterate();
        iterate();
        if (k == 1) iterate();   // no extrapolation history at k=1

        yppA = ypA; yppB = ypB;
        ypA = yA;   ypB = yB;

        float* op = out + ((size_t)k * NB + gb) * NS;
        __builtin_nontemporal_store(yA, (f32x4*)(op + 4 * h));
        __builtin_nontemporal_store(yB, (f32x4*)(op + 16 + 4 * h));
    }
}

extern "C" void kernel_launch(void* const* d_in, const int* in_sizes, int n_in,
                              void* d_out, int out_size, void* d_ws, size_t ws_size,
                              hipStream_t stream) {
    const float* y0     = (const float*)d_in[0];
    const float* forces = (const float*)d_in[1];
    const float* W      = (const float*)d_in[2];
    const float* U      = (const float*)d_in[3];
    const float* b      = (const float*)d_in[4];
    float* out = (float*)d_out;

    dim3 grid(NB / 16);   // 512 blocks x 1 wave x 16 batches = 8192
    dim3 block(64);
    rnes_kernel<<<grid, block, 0, stream>>>(y0, forces, W, U, b, out);
}